// Round 11
// baseline (327.146 us; speedup 1.0000x reference)
//
#include <hip/hip_runtime.h>
#include <stdint.h>

#define TT 512
#define XSTR 516  // x row stride (floats)

typedef float    f32x4 __attribute__((ext_vector_type(4)));
typedef float    f32x2 __attribute__((ext_vector_type(2)));
typedef short    s16x8 __attribute__((ext_vector_type(8)));
typedef __fp16   h16x2 __attribute__((ext_vector_type(2)));
typedef _Float16 f16x8 __attribute__((ext_vector_type(8)));

#define MFMA_F16(A, B, C) \
    __builtin_amdgcn_mfma_f32_16x16x32_f16( \
        __builtin_bit_cast(f16x8, (A)), (B), (C), 0, 0, 0)

#define LOG2E  1.442695040888963f
#define LOG2E2 2.885390081777927f

// R17: pace-pinned dual-set anti-phase. Evidence: wall 728 = issue(400,
// contended) + chain(330, both idle) -- the two R9 wgs run IN PHASE
// (diffusive offset). Fix: one 512-thread wg/CU, sets A=waves0-3,
// B=waves4-7 (round-robin pairs A+B per SIMD). Per-set 4-wave SOFT
// barriers (LDS counters, fenced) -> independent phases; B pinned one
// step behind A via a pace flag A writes mid-step: B's issue lands in
// A's chain window by construction (stable, not diffusive). Pace is
// heuristic-only (B never reads A's data). Step body = R9's 153us
// champion verbatim (chained MFMA, swizzled zero-conflict exchange,
// f32x2 math, pkrtz write). Null-case ~= current wall (A free-runs).
__global__ __launch_bounds__(512, 1) void gru_scan_kernel(
    const float* __restrict__ x,     // (4096, 512, 1)
    const float* __restrict__ Wih,   // (192, 1)
    const float* __restrict__ Whh,   // (192, 64)
    const float* __restrict__ bih,   // (192)
    const float* __restrict__ bhh,   // (192)
    const float* __restrict__ Wout,  // (1, 64)
    const float* __restrict__ bout,  // (1)
    float* __restrict__ out)         // (4096, 1)
{
    __shared__ __align__(16) float xs[16 * XSTR];     // 33 KB
    __shared__ __align__(16) short hbuf[2][2][1024];  // [set][dbuf], 8 KB
    __shared__ int   cnt[2][4];                       // soft-barrier counters
    __shared__ int   pace;                            // A's step pace
    __shared__ float outp[8][8];

    const int tid  = threadIdx.x;
    const int w    = tid >> 6;        // 0..7
    const int set  = w >> 2;          // 0 = A, 1 = B
    const int wv   = w & 3;           // wave within set
    const int L    = tid & 63;
    const int n16  = L & 15;
    const int quad = L >> 4;
    const int q    = wv * 16 + n16;   // hidden col owned by this lane
    const int bb0  = blockIdx.x * 16;

    // ---- stage x batch-major: xs[b][t] (2048 f32x4, 4 per thread) ----
    #pragma unroll
    for (int k = 0; k < 4; ++k) {
        int idx = tid + k * 512;          // 0..2047
        int row = idx >> 7;               // batch row 0..15
        int t4  = idx & 127;              // t/4
        f32x4 v = *(const f32x4*)(x + (size_t)(bb0 + row) * TT + t4 * 4);
        *(f32x4*)(xs + row * XSTR + t4 * 4) = v;
    }
    // ---- zero all h buffers (2048 u32) + sync primitives ----
    {
        unsigned* hz = (unsigned*)hbuf;
        #pragma unroll
        for (int k = 0; k < 4; ++k) hz[tid + k * 512] = 0u;
    }
    if (tid < 8) ((int*)cnt)[tid] = 0;
    if (tid == 8) pace = 0;

    // ---- per-lane constants (gate scales folded) ----
    const float wr2   = -LOG2E  * Wih[q];
    const float wz2   = -LOG2E  * Wih[64 + q];
    const float wn2   =  LOG2E2 * Wih[128 + q];
    const float bR2   = -LOG2E  * (bih[q]      + bhh[q]);
    const float bZ2   = -LOG2E  * (bih[64 + q] + bhh[64 + q]);
    const float bN2   =  LOG2E2 * bhh[128 + q];
    const float bihn2 =  LOG2E2 * bih[128 + q];
    const float wo    = Wout[q];

    const f32x4 bR4 = {bR2, bR2, bR2, bR2};
    const f32x4 bZ4 = {bZ2, bZ2, bZ2, bZ2};
    const f32x4 bN4 = {bN2, bN2, bN2, bN2};

    // ---- W_hh B-fragments (scaled), fp16 RNE ----
    f16x8 Bf[3][2];
    #pragma unroll
    for (int g = 0; g < 3; ++g) {
        const float sg = (g == 2) ? LOG2E2 : -LOG2E;
        #pragma unroll
        for (int c = 0; c < 2; ++c) {
            const float* p = Whh + ((g * 64 + q) * 64 + c * 32 + quad * 8);
            #pragma unroll
            for (int j = 0; j < 8; ++j)
                Bf[g][c][j] = (_Float16)(p[j] * sg);
        }
    }

    // persistent h (fp32): lane handles set batches quad*2 + {0,1}
    float hD[2] = {0.f, 0.f};

    // ---- R9's proven zero-conflict exchange addressing ----
    const int kg   = q >> 3;
    const int sxor = (kg & 1) * 4;
    int waddr[2];
    #pragma unroll
    for (int p = 0; p < 2; ++p)
        waddr[p] = (kg * 16 + ((p * 4 + quad) ^ sxor)) * 8 + (q & 7);

    const int permx = ((n16 & 3) * 4 + (n16 >> 2)) ^ ((quad & 1) * 4);
    const int rslot = quad * 16 + permx;

    const s16x8* hbv = (const s16x8*)hbuf[set];   // 256 slots of 8 shorts
    const float* xrow0 = xs + (set * 8 + quad * 2) * XSTR;
    const float* xrow1 = xrow0 + XSTR;

    __syncthreads();   // xs + hbuf + cnt/pace visible (one-time hard barrier)

    // ---- per-set 4-wave soft barrier ----
    auto sbar = [&](int v) {
        __threadfence_block();                       // h-writes visible first
        if (L == 0) ((volatile int*)cnt[set])[wv] = v;
        volatile int* c = (volatile int*)cnt[set];
        while (c[0] < v || c[1] < v || c[2] < v || c[3] < v) { }
        __threadfence_block();                       // no read hoisting
    };

    int s = 0;
    for (int t = 0; t < TT; t += 4) {
        f32x4 xa = *(const f32x4*)(xrow0 + t);   // batch b0, steps t..t+3
        f32x4 xb = *(const f32x4*)(xrow1 + t);   // batch b1, steps t..t+3
        #pragma unroll
        for (int j = 0; j < 4; ++j) {
            f32x2 xv = {xa[j], xb[j]};
            ++s;

            // B pinned one step behind A (binding wait, sleep-polled)
            if (set) {
                volatile int* pp = &pace;
                while (*pp < s + 1) __builtin_amdgcn_s_sleep(1);
            }
            sbar(s);

            const int cur = (s - 1) & 1;
            s16x8 A0 = hbv[cur * 128 +  0 + rslot];
            s16x8 A1 = hbv[cur * 128 + 64 + rslot];

            // r-gate first (heads the serial chain), z last (R9 order)
            f32x4 aR = MFMA_F16(A0, Bf[0][0], bR4);
            aR       = MFMA_F16(A1, Bf[0][1], aR);
            f32x4 aN = MFMA_F16(A0, Bf[2][0], bN4);
            aN       = MFMA_F16(A1, Bf[2][1], aN);
            f32x4 aZ = MFMA_F16(A0, Bf[1][0], bZ4);
            aZ       = MFMA_F16(A1, Bf[1][1], aZ);

            // A announces "entered step s" after its MFMA issue
            if (!set && w == 0 && L == 0) *(volatile int*)&pace = s;

            f32x2 aRp = {aR[0], aR[1]};
            f32x2 aZp = {aZ[0], aZ[1]};
            f32x2 aNp = {aN[0], aN[1]};
            f32x2 hp  = {hD[0], hD[1]};

            f32x2 ar = xv * wr2 + aRp;
            f32x2 Er = {__builtin_amdgcn_exp2f(ar[0]), __builtin_amdgcn_exp2f(ar[1])};
            f32x2 DR = Er + 1.0f;
            f32x2 r  = {__builtin_amdgcn_rcpf(DR[0]), __builtin_amdgcn_rcpf(DR[1])};
            f32x2 az = xv * wz2 + aZp;
            f32x2 Ez = {__builtin_amdgcn_exp2f(az[0]), __builtin_amdgcn_exp2f(az[1])};
            f32x2 DZ = Ez + 1.0f;
            f32x2 xn = xv * wn2 + bihn2;
            f32x2 an = r * aNp + xn;
            f32x2 En = {__builtin_amdgcn_exp2f(an[0]), __builtin_amdgcn_exp2f(an[1])};
            f32x2 DN = En + 1.0f;
            f32x2 P  = DZ * DN;
            f32x2 iq = {__builtin_amdgcn_rcpf(P[0]), __builtin_amdgcn_rcpf(P[1])};
            f32x2 z  = iq * DN;                  // = 1/DZ = sigmoid(pre_z)
            f32x2 rn = iq * DZ;                  // = 1/DN
            f32x2 n  = rn * -2.0f + 1.0f;        // tanh
            f32x2 hn = z * (hp - n) + n;         // (1-z)n + z h

            hD[0] = hn[0]; hD[1] = hn[1];

            h16x2 hpk = __builtin_amdgcn_cvt_pkrtz(hn[0], hn[1]);
            unsigned upk = __builtin_bit_cast(unsigned, hpk);
            short* wh = (short*)hbuf[set] + (cur ^ 1) * 1024;
            wh[waddr[0]] = (short)(upk & 0xffffu);
            wh[waddr[1]] = (short)(upk >> 16);
        }
    }
    // release B's final wait (pace >= TT+1)
    if (!set && w == 0 && L == 0) *(volatile int*)&pace = TT + 1;

    // ---- epilogue: out[b] = sum_q h[b][q]*Wout[q] + bout ----
    float p0 = hD[0] * wo;
    float p1 = hD[1] * wo;
    #pragma unroll
    for (int mask = 1; mask <= 8; mask <<= 1) {
        p0 += __shfl_xor(p0, mask, 64);
        p1 += __shfl_xor(p1, mask, 64);
    }
    if (n16 == 0) {
        outp[w][quad * 2]     = p0;
        outp[w][quad * 2 + 1] = p1;
    }
    __syncthreads();
    if (tid < 16) {
        int ss = tid >> 3;        // set
        int c  = tid & 7;         // batch within set
        out[bb0 + tid] = outp[ss * 4 + 0][c] + outp[ss * 4 + 1][c] +
                         outp[ss * 4 + 2][c] + outp[ss * 4 + 3][c] + bout[0];
    }
}

extern "C" void kernel_launch(void* const* d_in, const int* in_sizes, int n_in,
                              void* d_out, int out_size, void* d_ws, size_t ws_size,
                              hipStream_t stream) {
    (void)in_sizes; (void)n_in; (void)d_ws; (void)ws_size; (void)out_size;
    const float* x    = (const float*)d_in[0];
    const float* Wih  = (const float*)d_in[1];
    const float* Whh  = (const float*)d_in[2];
    const float* bih  = (const float*)d_in[3];
    const float* bhh  = (const float*)d_in[4];
    const float* Wout = (const float*)d_in[5];
    const float* bout = (const float*)d_in[6];
    float* out = (float*)d_out;

    gru_scan_kernel<<<dim3(4096 / 16), dim3(512), 0, stream>>>(
        x, Wih, Whh, bih, bhh, Wout, bout, out);
}